// Round 6
// baseline (808.399 us; speedup 1.0000x reference)
//
#include <hip/hip_runtime.h>

typedef __attribute__((ext_vector_type(8))) short bf16x8;
typedef __attribute__((ext_vector_type(4))) float f32x4;

#define PWS 72   // LDS tile pitch in shorts: 144B rows, 16B-aligned chunks

__device__ __forceinline__ float silu_f(float v) {
    return v * (1.0f / (1.0f + __expf(-v)));
}

// split f32 into hi (bf16 truncation, exact residual) + lo (bf16 of residual)
__device__ __forceinline__ void split_bf(float f, short& h, short& l) {
    unsigned u = __float_as_uint(f);
    h = (short)(u >> 16);
    float res = f - __uint_as_float(u & 0xffff0000u);   // exact
    l = (short)(__float_as_uint(res) >> 16);
}

// ---------------------------------------------------------------------------
// Weight pre-conversion: fp32 [K][64] -> hi/lo bf16 in B-fragment order:
//   out[((t*4+nf)*64 + lane)*8 + j] = W[t*32 + (lane>>4)*8 + j][nf*16 + (lane&15)]
// ---------------------------------------------------------------------------
struct WDesc { const float* W; short* hi; short* lo; int K; };
struct WPack { WDesc d[8]; };

__global__ __launch_bounds__(256) void conv_weights(WPack p) {
    WDesc wd = p.d[blockIdx.y];
    int total = wd.K * 64;
    int i = blockIdx.x * 256 + threadIdx.x;
    if (i >= total) return;
    int j  = i & 7;
    int l  = (i >> 3) & 63;
    int tn = i >> 9;                 // t*4 + nf
    int t  = tn >> 2, nf = tn & 3;
    int k  = t * 32 + (l >> 4) * 8 + j;
    int c  = nf * 16 + (l & 15);
    float f = wd.W[k * 64 + c];
    unsigned u = __float_as_uint(f);
    short h = (short)(u >> 16);
    float res = f - __uint_as_float(u & 0xffff0000u);
    unsigned ur = __float_as_uint(res);
    short lo16 = (short)((ur + 0x7fffu + ((ur >> 16) & 1u)) >> 16);  // RNE
    wd.hi[i] = h;
    wd.lo[i] = lo16;
}

// ---------------------------------------------------------------------------
// Edge kernel: 4 independent waves/block, wave owns 16 edges. ALL 12 float4
// loads (3 segments, 256B-coalesced per 4 rows) issued upfront into registers
// -> one global round-trip. Convert->LDS->MFMA per segment (buffer reused,
// wave-private rows, no barriers). Epilogue: plain ea_out stores + transposed
// atomic scatter into agg (lane = channel -> 64 consecutive dwords / instr).
// ---------------------------------------------------------------------------
__global__ __launch_bounds__(256, 8) void gnn_edge_mfma(
    const float* __restrict__ x,
    const float* __restrict__ ea_in,
    float* __restrict__ ea_out,
    const int* __restrict__ src_idx,
    const int* __restrict__ dst_idx,
    const short* __restrict__ w1h, const short* __restrict__ w1l,
    const float* __restrict__ b1,
    const short* __restrict__ w2h, const short* __restrict__ w2l,
    const float* __restrict__ b2,
    float* __restrict__ agg,
    int E)
{
    __shared__ __align__(16) short s_hi[64][PWS];
    __shared__ __align__(16) short s_lo[64][PWS];

    const int t    = threadIdx.x;
    const int lane = t & 63;
    const int w    = t >> 6;
    const int col  = lane & 15;
    const int g    = lane >> 4;
    const int ko   = g * 8;
    const long base = (long)blockIdx.x * 64;

    // this lane's own A-row (edge id) — dst kept for the shfl'd epilogue
    long er0 = base + w * 16 + col;
    if (er0 >= E) er0 = E - 1;
    const int di = dst_idx[er0];

    // ---- upfront loads: rows it*4+g of the wave tile, cols col*4..+4 ----
    float4 ea4[4], sx4[4], dx4[4];
#pragma unroll
    for (int it = 0; it < 4; ++it) {
        long er = base + w * 16 + it * 4 + g;
        if (er >= E) er = E - 1;
        ea4[it] = *(const float4*)(ea_in + er * 64 + col * 4);
        sx4[it] = *(const float4*)(x + (long)src_idx[er] * 64 + col * 4);
        dx4[it] = *(const float4*)(x + (long)dst_idx[er] * 64 + col * 4);
    }

    f32x4 acc[4];
#pragma unroll
    for (int nf = 0; nf < 4; ++nf) {
        float bv = b1[nf * 16 + col];
        acc[nf] = (f32x4){bv, bv, bv, bv};
    }

    const int arow = w * 16 + col;

#define SEGMENT(s3, SRC)                                                        \
    {                                                                           \
        _Pragma("unroll")                                                       \
        for (int it = 0; it < 4; ++it) {                                        \
            int rg = w * 16 + it * 4 + g;                                       \
            short h0,l0,h1,l1,h2,l2,h3,l3;                                      \
            split_bf(SRC[it].x, h0, l0); split_bf(SRC[it].y, h1, l1);           \
            split_bf(SRC[it].z, h2, l2); split_bf(SRC[it].w, h3, l3);           \
            *(short4*)&s_hi[rg][col * 4] = make_short4(h0, h1, h2, h3);         \
            *(short4*)&s_lo[rg][col * 4] = make_short4(l0, l1, l2, l3);         \
        }                                                                       \
        _Pragma("unroll")                                                       \
        for (int tt = 0; tt < 2; ++tt) {                                        \
            int k0 = tt * 32 + ko;                                              \
            bf16x8 ahi = *(const bf16x8*)&s_hi[arow][k0];                       \
            bf16x8 alo = *(const bf16x8*)&s_lo[arow][k0];                       \
            int tg = (s3) * 2 + tt;                                             \
            _Pragma("unroll")                                                   \
            for (int nf = 0; nf < 4; ++nf) {                                    \
                bf16x8 bh = *(const bf16x8*)(w1h + (size_t)((tg*4+nf)*64+lane)*8); \
                bf16x8 bl = *(const bf16x8*)(w1l + (size_t)((tg*4+nf)*64+lane)*8); \
                acc[nf] = __builtin_amdgcn_mfma_f32_16x16x32_bf16(ahi, bh, acc[nf], 0, 0, 0); \
                acc[nf] = __builtin_amdgcn_mfma_f32_16x16x32_bf16(ahi, bl, acc[nf], 0, 0, 0); \
                acc[nf] = __builtin_amdgcn_mfma_f32_16x16x32_bf16(alo, bh, acc[nf], 0, 0, 0); \
            }                                                                   \
        }                                                                       \
    }

    SEGMENT(0, ea4)    // edge_attr  (k 0..63)
    SEGMENT(1, sx4)    // x[src]     (k 64..127)
    SEGMENT(2, dx4)    // x[dst]     (k 128..191)
#undef SEGMENT

    // ---- silu -> h staged into the wave's own 16 LDS rows (C-frag layout) ----
#pragma unroll
    for (int nf = 0; nf < 4; ++nf)
#pragma unroll
        for (int rg = 0; rg < 4; ++rg) {
            int row = w * 16 + g * 4 + rg;
            short hh, hl;
            split_bf(silu_f(acc[nf][rg]), hh, hl);
            s_hi[row][nf * 16 + col] = hh;
            s_lo[row][nf * 16 + col] = hl;
        }

    // ---- layer-2 GEMM (K=64) ----
    f32x4 out[4];
#pragma unroll
    for (int nf = 0; nf < 4; ++nf) {
        float bv = b2[nf * 16 + col];
        out[nf] = (f32x4){bv, bv, bv, bv};
    }
#pragma unroll
    for (int tt = 0; tt < 2; ++tt) {
        int k0 = tt * 32 + ko;
        bf16x8 ahi = *(const bf16x8*)&s_hi[arow][k0];
        bf16x8 alo = *(const bf16x8*)&s_lo[arow][k0];
#pragma unroll
        for (int nf = 0; nf < 4; ++nf) {
            bf16x8 bh = *(const bf16x8*)(w2h + (size_t)((tt * 4 + nf) * 64 + lane) * 8);
            bf16x8 bl = *(const bf16x8*)(w2l + (size_t)((tt * 4 + nf) * 64 + lane) * 8);
            out[nf] = __builtin_amdgcn_mfma_f32_16x16x32_bf16(ahi, bh, out[nf], 0, 0, 0);
            out[nf] = __builtin_amdgcn_mfma_f32_16x16x32_bf16(ahi, bl, out[nf], 0, 0, 0);
            out[nf] = __builtin_amdgcn_mfma_f32_16x16x32_bf16(alo, bh, out[nf], 0, 0, 0);
        }
    }

    // ---- epilogue: plain stores + transposed atomic scatter ----
    // Each atomic instruction: 64 lanes hit 64 consecutive dwords of one
    // 16-row group's dst row -> 4 cache lines (not 64).
    const int rbase = w * 16 + g * 4;
#pragma unroll
    for (int rg = 0; rg < 4; ++rg) {
        long row = base + rbase + rg;
        if (row < E) {
            int drow = __shfl(di, g * 4 + rg);   // lane col==g*4+rg holds this row's dst
            float* op = ea_out + row * 64;
            float* ap = agg + (long)drow * 64;
#pragma unroll
            for (int nf = 0; nf < 4; ++nf) {
                op[nf * 16 + col] = out[nf][rg];
                atomicAdd(&ap[nf * 16 + col], out[nf][rg]);
            }
        }
    }
}

// ---------------------------------------------------------------------------
// Node kernel: direct A-fragment loads (x, agg rows sequential -> dense pairs),
// LDS only for the h transpose. No atomics.
// ---------------------------------------------------------------------------
__global__ __launch_bounds__(256, 8) void gnn_node_mfma(
    const float* __restrict__ x_in,
    const float* __restrict__ aggp,
    float* __restrict__ x_out,
    const short* __restrict__ w1h, const short* __restrict__ w1l,
    const float* __restrict__ b1,
    const short* __restrict__ w2h, const short* __restrict__ w2l,
    const float* __restrict__ b2, int N)
{
    __shared__ __align__(16) short h_hi[64][PWS];
    __shared__ __align__(16) short h_lo[64][PWS];

    const int t    = threadIdx.x;
    const int lane = t & 63;
    const int w    = t >> 6;
    const int col  = lane & 15;
    const int g    = lane >> 4;
    const int ko   = g * 8;
    const long base = (long)blockIdx.x * 64;

    long nr = base + w * 16 + col;
    if (nr >= N) nr = N - 1;
    const float* px = x_in + nr * 64 + ko;
    const float* pa = aggp + nr * 64 + ko;

    float4 v0 = *(const float4*)(px);
    float4 v1 = *(const float4*)(px + 4);
    float4 v2 = *(const float4*)(px + 32);
    float4 v3 = *(const float4*)(px + 36);
    float4 v4 = *(const float4*)(pa);
    float4 v5 = *(const float4*)(pa + 4);
    float4 v6 = *(const float4*)(pa + 32);
    float4 v7 = *(const float4*)(pa + 36);

    f32x4 acc[4];
#pragma unroll
    for (int nf = 0; nf < 4; ++nf) {
        float bv = b1[nf * 16 + col];
        acc[nf] = (f32x4){bv, bv, bv, bv};
    }

#define QTR(m, A, B)                                                            \
    {                                                                           \
        bf16x8 ah, al;                                                          \
        short hh, ll;                                                           \
        split_bf(A.x, hh, ll); ah[0]=hh; al[0]=ll;                              \
        split_bf(A.y, hh, ll); ah[1]=hh; al[1]=ll;                              \
        split_bf(A.z, hh, ll); ah[2]=hh; al[2]=ll;                              \
        split_bf(A.w, hh, ll); ah[3]=hh; al[3]=ll;                              \
        split_bf(B.x, hh, ll); ah[4]=hh; al[4]=ll;                              \
        split_bf(B.y, hh, ll); ah[5]=hh; al[5]=ll;                              \
        split_bf(B.z, hh, ll); ah[6]=hh; al[6]=ll;                              \
        split_bf(B.w, hh, ll); ah[7]=hh; al[7]=ll;                              \
        _Pragma("unroll")                                                       \
        for (int nf = 0; nf < 4; ++nf) {                                        \
            bf16x8 bh = *(const bf16x8*)(w1h + (size_t)(((m)*4+nf)*64+lane)*8); \
            bf16x8 bl = *(const bf16x8*)(w1l + (size_t)(((m)*4+nf)*64+lane)*8); \
            acc[nf] = __builtin_amdgcn_mfma_f32_16x16x32_bf16(ah, bh, acc[nf], 0, 0, 0); \
            acc[nf] = __builtin_amdgcn_mfma_f32_16x16x32_bf16(ah, bl, acc[nf], 0, 0, 0); \
            acc[nf] = __builtin_amdgcn_mfma_f32_16x16x32_bf16(al, bh, acc[nf], 0, 0, 0); \
        }                                                                       \
    }
    QTR(0, v0, v1)  QTR(1, v2, v3)   // x    (k 0..63)
    QTR(2, v4, v5)  QTR(3, v6, v7)   // agg  (k 64..127)
#undef QTR

#pragma unroll
    for (int nf = 0; nf < 4; ++nf)
#pragma unroll
        for (int rg = 0; rg < 4; ++rg) {
            int row = w * 16 + g * 4 + rg;
            short hh, hl;
            split_bf(silu_f(acc[nf][rg]), hh, hl);
            h_hi[row][nf * 16 + col] = hh;
            h_lo[row][nf * 16 + col] = hl;
        }

    f32x4 out[4];
#pragma unroll
    for (int nf = 0; nf < 4; ++nf) {
        float bv = b2[nf * 16 + col];
        out[nf] = (f32x4){bv, bv, bv, bv};
    }
    const int arow = w * 16 + col;
#pragma unroll
    for (int tt = 0; tt < 2; ++tt) {
        int k0 = tt * 32 + ko;
        bf16x8 ahi = *(const bf16x8*)&h_hi[arow][k0];
        bf16x8 alo = *(const bf16x8*)&h_lo[arow][k0];
#pragma unroll
        for (int nf = 0; nf < 4; ++nf) {
            bf16x8 bh = *(const bf16x8*)(w2h + (size_t)((tt * 4 + nf) * 64 + lane) * 8);
            bf16x8 bl = *(const bf16x8*)(w2l + (size_t)((tt * 4 + nf) * 64 + lane) * 8);
            out[nf] = __builtin_amdgcn_mfma_f32_16x16x32_bf16(ahi, bh, out[nf], 0, 0, 0);
            out[nf] = __builtin_amdgcn_mfma_f32_16x16x32_bf16(ahi, bl, out[nf], 0, 0, 0);
            out[nf] = __builtin_amdgcn_mfma_f32_16x16x32_bf16(alo, bh, out[nf], 0, 0, 0);
        }
    }

    const int rbase = w * 16 + g * 4;
#pragma unroll
    for (int rg = 0; rg < 4; ++rg) {
        long row = base + rbase + rg;
        if (row < N) {
            float* op = x_out + row * 64;
#pragma unroll
            for (int nf = 0; nf < 4; ++nf)
                op[nf * 16 + col] = out[nf][rg];
        }
    }
}

extern "C" void kernel_launch(void* const* d_in, const int* in_sizes, int n_in,
                              void* d_out, int out_size, void* d_ws, size_t ws_size,
                              hipStream_t stream) {
    const int H = 64;
    const int N = in_sizes[0] / H;   // 50000
    const int E = in_sizes[1] / H;   // 800000

    const float* x0  = (const float*)d_in[0];
    const float* ea0 = (const float*)d_in[1];
    const int*   ei  = (const int*)d_in[2];
    const float* ew1 = (const float*)d_in[3];
    const float* eb1 = (const float*)d_in[4];
    const float* ew2 = (const float*)d_in[5];
    const float* eb2 = (const float*)d_in[6];
    const float* nw1 = (const float*)d_in[7];
    const float* nb1 = (const float*)d_in[8];
    const float* nw2 = (const float*)d_in[9];
    const float* nb2 = (const float*)d_in[10];

    float* outX = (float*)d_out;                 // [N, H]
    float* outE = outX + (size_t)N * H;          // [E, H]

    float* agg   = (float*)d_ws;                 // [N, H] fp32
    short* wbase = (short*)(agg + (size_t)N * H);

    const int* srcI = ei;
    const int* dstI = ei + E;

    WPack pack;
    size_t off = 0;
    short* EH[2]; short* EL[2]; short* E2H[2]; short* E2L[2];
    short* NH[2]; short* NL[2]; short* N2H[2]; short* N2L[2];
    for (int l = 0; l < 2; ++l) {
        EH[l]  = wbase + off; off += 192 * 64;
        EL[l]  = wbase + off; off += 192 * 64;
        E2H[l] = wbase + off; off += 64 * 64;
        E2L[l] = wbase + off; off += 64 * 64;
        NH[l]  = wbase + off; off += 128 * 64;
        NL[l]  = wbase + off; off += 128 * 64;
        N2H[l] = wbase + off; off += 64 * 64;
        N2L[l] = wbase + off; off += 64 * 64;
        pack.d[l * 4 + 0] = {ew1 + (size_t)l * 192 * 64, EH[l],  EL[l],  192};
        pack.d[l * 4 + 1] = {ew2 + (size_t)l * 64 * 64,  E2H[l], E2L[l], 64};
        pack.d[l * 4 + 2] = {nw1 + (size_t)l * 128 * 64, NH[l],  NL[l],  128};
        pack.d[l * 4 + 3] = {nw2 + (size_t)l * 64 * 64,  N2H[l], N2L[l], 64};
    }
    conv_weights<<<dim3(48, 8), 256, 0, stream>>>(pack);

    const int egrid = (E + 63) / 64;
    const int ngrid = (N + 63) / 64;
    const size_t aggBytes = (size_t)N * H * sizeof(float);

    for (int l = 0; l < 2; ++l) {
        const float* xin  = (l == 0) ? x0  : outX;
        const float* eain = (l == 0) ? ea0 : outE;
        hipMemsetAsync(agg, 0, aggBytes, stream);
        gnn_edge_mfma<<<egrid, 256, 0, stream>>>(
            xin, eain, outE, srcI, dstI,
            EH[l], EL[l], eb1 + l * H,
            E2H[l], E2L[l], eb2 + l * H,
            agg, E);
        gnn_node_mfma<<<ngrid, 256, 0, stream>>>(
            xin, agg, outX,
            NH[l], NL[l], nb1 + l * H,
            N2H[l], N2L[l], nb2 + l * H,
            N);
    }
}

// Round 8
// 578.906 us; speedup vs baseline: 1.3964x; 1.3964x over previous
//
#include <hip/hip_runtime.h>

typedef __attribute__((ext_vector_type(8))) _Float16 f16x8;
typedef __attribute__((ext_vector_type(4))) _Float16 f16x4;
typedef __attribute__((ext_vector_type(4))) float f32x4;

#define PWS 72   // LDS tile pitch in halfs: 144B rows, 16B-aligned chunks

__device__ __forceinline__ float silu_f(float v) {
    return v * (1.0f / (1.0f + __expf(-v)));
}

// ---------------------------------------------------------------------------
// Weight pre-conversion: fp32 [K][64] -> f16 in B-fragment order:
//   out[((t*4+nf)*64 + lane)*8 + j] = W[t*32 + (lane>>4)*8 + j][nf*16 + (lane&15)]
// ---------------------------------------------------------------------------
struct WDesc { const float* W; _Float16* out; int K; };
struct WPack { WDesc d[8]; };

__global__ __launch_bounds__(256) void conv_weights(WPack p) {
    WDesc wd = p.d[blockIdx.y];
    int total = wd.K * 64;
    int i = blockIdx.x * 256 + threadIdx.x;
    if (i >= total) return;
    int j  = i & 7;
    int l  = (i >> 3) & 63;
    int tn = i >> 9;                 // t*4 + nf
    int t  = tn >> 2, nf = tn & 3;
    int k  = t * 32 + (l >> 4) * 8 + j;
    int c  = nf * 16 + (l & 15);
    wd.out[i] = (_Float16)wd.W[k * 64 + c];   // RNE
}

// ---------------------------------------------------------------------------
// Edge kernel: 4 independent waves/block, wave owns 16 edges. ALL 12 float4
// loads (3 segments, 256B-coalesced per 4 rows) issued upfront into registers
// -> one global round-trip. Convert to f16 -> LDS -> MFMA per segment
// (buffer reused, wave-private rows, no barriers). Single-pass f16 MFMA.
// Epilogue: plain ea_out stores + transposed atomic scatter into agg.
// ---------------------------------------------------------------------------
__global__ __launch_bounds__(256, 4) void gnn_edge_mfma(
    const float* __restrict__ x,
    const float* __restrict__ ea_in,
    float* __restrict__ ea_out,
    const int* __restrict__ src_idx,
    const int* __restrict__ dst_idx,
    const _Float16* __restrict__ w1f,
    const float* __restrict__ b1,
    const _Float16* __restrict__ w2f,
    const float* __restrict__ b2,
    float* __restrict__ agg,
    int E)
{
    __shared__ __align__(16) _Float16 sA[64][PWS];

    const int t    = threadIdx.x;
    const int lane = t & 63;
    const int w    = t >> 6;
    const int col  = lane & 15;
    const int g    = lane >> 4;
    const int ko   = g * 8;
    const long base = (long)blockIdx.x * 64;

    // this lane's own A-row (edge id) — dst kept for the shfl'd epilogue
    long er0 = base + w * 16 + col;
    if (er0 >= E) er0 = E - 1;
    const int di = dst_idx[er0];

    // ---- upfront loads: rows it*4+g of the wave tile, cols col*4..+4 ----
    float4 ea4[4], sx4[4], dx4[4];
#pragma unroll
    for (int it = 0; it < 4; ++it) {
        long er = base + w * 16 + it * 4 + g;
        if (er >= E) er = E - 1;
        ea4[it] = *(const float4*)(ea_in + er * 64 + col * 4);
        sx4[it] = *(const float4*)(x + (long)src_idx[er] * 64 + col * 4);
        dx4[it] = *(const float4*)(x + (long)dst_idx[er] * 64 + col * 4);
    }

    f32x4 acc[4];
#pragma unroll
    for (int nf = 0; nf < 4; ++nf) {
        float bv = b1[nf * 16 + col];
        acc[nf] = (f32x4){bv, bv, bv, bv};
    }

    const int arow = w * 16 + col;

#define SEGMENT(s3, SRC)                                                        \
    {                                                                           \
        _Pragma("unroll")                                                       \
        for (int it = 0; it < 4; ++it) {                                        \
            int rg = w * 16 + it * 4 + g;                                       \
            f16x4 hv;                                                           \
            hv[0] = (_Float16)SRC[it].x; hv[1] = (_Float16)SRC[it].y;           \
            hv[2] = (_Float16)SRC[it].z; hv[3] = (_Float16)SRC[it].w;           \
            *(f16x4*)&sA[rg][col * 4] = hv;                                     \
        }                                                                       \
        _Pragma("unroll")                                                       \
        for (int tt = 0; tt < 2; ++tt) {                                        \
            int k0 = tt * 32 + ko;                                              \
            f16x8 af = *(const f16x8*)&sA[arow][k0];                            \
            int tg = (s3) * 2 + tt;                                             \
            _Pragma("unroll")                                                   \
            for (int nf = 0; nf < 4; ++nf) {                                    \
                f16x8 bf = *(const f16x8*)(w1f + (size_t)((tg*4+nf)*64+lane)*8);\
                acc[nf] = __builtin_amdgcn_mfma_f32_16x16x32_f16(af, bf, acc[nf], 0, 0, 0); \
            }                                                                   \
        }                                                                       \
    }

    SEGMENT(0, ea4)    // edge_attr  (k 0..63)
    SEGMENT(1, sx4)    // x[src]     (k 64..127)
    SEGMENT(2, dx4)    // x[dst]     (k 128..191)
#undef SEGMENT

    // ---- silu -> h staged into the wave's own 16 LDS rows (C-frag layout) ----
#pragma unroll
    for (int nf = 0; nf < 4; ++nf)
#pragma unroll
        for (int rg = 0; rg < 4; ++rg) {
            int row = w * 16 + g * 4 + rg;
            sA[row][nf * 16 + col] = (_Float16)silu_f(acc[nf][rg]);
        }

    // ---- layer-2 GEMM (K=64) ----
    f32x4 out[4];
#pragma unroll
    for (int nf = 0; nf < 4; ++nf) {
        float bv = b2[nf * 16 + col];
        out[nf] = (f32x4){bv, bv, bv, bv};
    }
#pragma unroll
    for (int tt = 0; tt < 2; ++tt) {
        int k0 = tt * 32 + ko;
        f16x8 af = *(const f16x8*)&sA[arow][k0];
#pragma unroll
        for (int nf = 0; nf < 4; ++nf) {
            f16x8 bf = *(const f16x8*)(w2f + (size_t)((tt * 4 + nf) * 64 + lane) * 8);
            out[nf] = __builtin_amdgcn_mfma_f32_16x16x32_f16(af, bf, out[nf], 0, 0, 0);
        }
    }

    // ---- epilogue: plain stores + transposed atomic scatter ----
    const int rbase = w * 16 + g * 4;
#pragma unroll
    for (int rg = 0; rg < 4; ++rg) {
        long row = base + rbase + rg;
        if (row < E) {
            int drow = __shfl(di, g * 4 + rg);   // lane col==g*4+rg holds this row's dst
            float* op = ea_out + row * 64;
            float* ap = agg + (long)drow * 64;
#pragma unroll
            for (int nf = 0; nf < 4; ++nf) {
                op[nf * 16 + col] = out[nf][rg];
                atomicAdd(&ap[nf * 16 + col], out[nf][rg]);
            }
        }
    }
}

// ---------------------------------------------------------------------------
// Node kernel: direct A-fragment loads (x, agg rows sequential), LDS only for
// the h transpose. Single-pass f16. No atomics.
// ---------------------------------------------------------------------------
__global__ __launch_bounds__(256, 4) void gnn_node_mfma(
    const float* __restrict__ x_in,
    const float* __restrict__ aggp,
    float* __restrict__ x_out,
    const _Float16* __restrict__ w1f,
    const float* __restrict__ b1,
    const _Float16* __restrict__ w2f,
    const float* __restrict__ b2, int N)
{
    __shared__ __align__(16) _Float16 sA[64][PWS];

    const int t    = threadIdx.x;
    const int lane = t & 63;
    const int w    = t >> 6;
    const int col  = lane & 15;
    const int g    = lane >> 4;
    const int ko   = g * 8;
    const long base = (long)blockIdx.x * 64;

    long nr = base + w * 16 + col;
    if (nr >= N) nr = N - 1;
    const float* px = x_in + nr * 64 + ko;
    const float* pa = aggp + nr * 64 + ko;

    float4 v0 = *(const float4*)(px);
    float4 v1 = *(const float4*)(px + 4);
    float4 v2 = *(const float4*)(px + 32);
    float4 v3 = *(const float4*)(px + 36);
    float4 v4 = *(const float4*)(pa);
    float4 v5 = *(const float4*)(pa + 4);
    float4 v6 = *(const float4*)(pa + 32);
    float4 v7 = *(const float4*)(pa + 36);

    f32x4 acc[4];
#pragma unroll
    for (int nf = 0; nf < 4; ++nf) {
        float bv = b1[nf * 16 + col];
        acc[nf] = (f32x4){bv, bv, bv, bv};
    }

#define QTR(m, A, B)                                                            \
    {                                                                           \
        f16x8 af;                                                               \
        af[0] = (_Float16)A.x; af[1] = (_Float16)A.y;                           \
        af[2] = (_Float16)A.z; af[3] = (_Float16)A.w;                           \
        af[4] = (_Float16)B.x; af[5] = (_Float16)B.y;                           \
        af[6] = (_Float16)B.z; af[7] = (_Float16)B.w;                           \
        _Pragma("unroll")                                                       \
        for (int nf = 0; nf < 4; ++nf) {                                        \
            f16x8 bf = *(const f16x8*)(w1f + (size_t)(((m)*4+nf)*64+lane)*8);   \
            acc[nf] = __builtin_amdgcn_mfma_f32_16x16x32_f16(af, bf, acc[nf], 0, 0, 0); \
        }                                                                       \
    }
    QTR(0, v0, v1)  QTR(1, v2, v3)   // x    (k 0..63)
    QTR(2, v4, v5)  QTR(3, v6, v7)   // agg  (k 64..127)
#undef QTR

#pragma unroll
    for (int nf = 0; nf < 4; ++nf)
#pragma unroll
        for (int rg = 0; rg < 4; ++rg) {
            int row = w * 16 + g * 4 + rg;
            sA[row][nf * 16 + col] = (_Float16)silu_f(acc[nf][rg]);
        }

    f32x4 out[4];
#pragma unroll
    for (int nf = 0; nf < 4; ++nf) {
        float bv = b2[nf * 16 + col];
        out[nf] = (f32x4){bv, bv, bv, bv};
    }
    const int arow = w * 16 + col;
#pragma unroll
    for (int tt = 0; tt < 2; ++tt) {
        int k0 = tt * 32 + ko;
        f16x8 af = *(const f16x8*)&sA[arow][k0];
#pragma unroll
        for (int nf = 0; nf < 4; ++nf) {
            f16x8 bf = *(const f16x8*)(w2f + (size_t)((tt * 4 + nf) * 64 + lane) * 8);
            out[nf] = __builtin_amdgcn_mfma_f32_16x16x32_f16(af, bf, out[nf], 0, 0, 0);
        }
    }

    const int rbase = w * 16 + g * 4;
#pragma unroll
    for (int rg = 0; rg < 4; ++rg) {
        long row = base + rbase + rg;
        if (row < N) {
            float* op = x_out + row * 64;
#pragma unroll
            for (int nf = 0; nf < 4; ++nf)
                op[nf * 16 + col] = out[nf][rg];
        }
    }
}

extern "C" void kernel_launch(void* const* d_in, const int* in_sizes, int n_in,
                              void* d_out, int out_size, void* d_ws, size_t ws_size,
                              hipStream_t stream) {
    const int H = 64;
    const int N = in_sizes[0] / H;   // 50000
    const int E = in_sizes[1] / H;   // 800000

    const float* x0  = (const float*)d_in[0];
    const float* ea0 = (const float*)d_in[1];
    const int*   ei  = (const int*)d_in[2];
    const float* ew1 = (const float*)d_in[3];
    const float* eb1 = (const float*)d_in[4];
    const float* ew2 = (const float*)d_in[5];
    const float* eb2 = (const float*)d_in[6];
    const float* nw1 = (const float*)d_in[7];
    const float* nb1 = (const float*)d_in[8];
    const float* nw2 = (const float*)d_in[9];
    const float* nb2 = (const float*)d_in[10];

    float* outX = (float*)d_out;                 // [N, H]
    float* outE = outX + (size_t)N * H;          // [E, H]

    float* agg      = (float*)d_ws;              // [N, H] fp32
    _Float16* wbase = (_Float16*)(agg + (size_t)N * H);

    const int* srcI = ei;
    const int* dstI = ei + E;

    WPack pack;
    size_t off = 0;
    _Float16* EW1[2]; _Float16* EW2[2]; _Float16* NW1[2]; _Float16* NW2[2];
    for (int l = 0; l < 2; ++l) {
        EW1[l] = wbase + off; off += 192 * 64;
        EW2[l] = wbase + off; off += 64 * 64;
        NW1[l] = wbase + off; off += 128 * 64;
        NW2[l] = wbase + off; off += 64 * 64;
        pack.d[l * 4 + 0] = {ew1 + (size_t)l * 192 * 64, EW1[l], 192};
        pack.d[l * 4 + 1] = {ew2 + (size_t)l * 64 * 64,  EW2[l], 64};
        pack.d[l * 4 + 2] = {nw1 + (size_t)l * 128 * 64, NW1[l], 128};
        pack.d[l * 4 + 3] = {nw2 + (size_t)l * 64 * 64,  NW2[l], 64};
    }
    conv_weights<<<dim3(48, 8), 256, 0, stream>>>(pack);

    const int egrid = (E + 63) / 64;
    const int ngrid = (N + 63) / 64;
    const size_t aggBytes = (size_t)N * H * sizeof(float);

    for (int l = 0; l < 2; ++l) {
        const float* xin  = (l == 0) ? x0  : outX;
        const float* eain = (l == 0) ? ea0 : outE;
        (void)hipMemsetAsync(agg, 0, aggBytes, stream);
        gnn_edge_mfma<<<egrid, 256, 0, stream>>>(
            xin, eain, outE, srcI, dstI,
            EW1[l], eb1 + l * H,
            EW2[l], eb2 + l * H,
            agg, E);
        gnn_node_mfma<<<ngrid, 256, 0, stream>>>(
            xin, agg, outX,
            NW1[l], nb1 + l * H,
            NW2[l], nb2 + l * H,
            N);
    }
}

// Round 9
// 540.442 us; speedup vs baseline: 1.4958x; 1.0712x over previous
//
#include <hip/hip_runtime.h>

typedef __attribute__((ext_vector_type(8))) _Float16 f16x8;
typedef __attribute__((ext_vector_type(4))) _Float16 f16x4;
typedef __attribute__((ext_vector_type(4))) float f32x4;

#define PWS 72   // LDS tile pitch in halfs: 144B rows, 16B-aligned chunks

__device__ __forceinline__ float silu_f(float v) {
    return v * (1.0f / (1.0f + __expf(-v)));
}

// ---------------------------------------------------------------------------
// Weight pre-conversion: fp32 [K][64] -> f16 in B-fragment order:
//   out[((t*4+nf)*64 + lane)*8 + j] = W[t*32 + (lane>>4)*8 + j][nf*16 + (lane&15)]
// ---------------------------------------------------------------------------
struct WDesc { const float* W; _Float16* out; int K; };
struct WPack { WDesc d[8]; };

__global__ __launch_bounds__(256) void conv_weights(WPack p) {
    WDesc wd = p.d[blockIdx.y];
    int total = wd.K * 64;
    int i = blockIdx.x * 256 + threadIdx.x;
    if (i >= total) return;
    int j  = i & 7;
    int l  = (i >> 3) & 63;
    int tn = i >> 9;                 // t*4 + nf
    int t  = tn >> 2, nf = tn & 3;
    int k  = t * 32 + (l >> 4) * 8 + j;
    int c  = nf * 16 + (l & 15);
    wd.out[i] = (_Float16)wd.W[k * 64 + c];   // RNE
}

// ---------------------------------------------------------------------------
// Edge kernel: 4 independent waves/block, wave owns 16 edges. ALL 12 float4
// loads (3 segments, 256B-coalesced per 4 rows) issued upfront into registers
// -> one global round-trip. Convert to f16 -> LDS -> MFMA per segment
// (buffer reused, wave-private rows, no barriers). Single-pass f16 MFMA.
// Epilogue: plain ea_out stores + transposed atomic scatter into agg.
// launch_bounds(256,8): f16 path needs only ~52 VGPR, so the 64-VGPR cap for
// 8 waves/EU is free -> double occupancy for this latency-bound kernel.
// ---------------------------------------------------------------------------
__global__ __launch_bounds__(256, 8) void gnn_edge_mfma(
    const float* __restrict__ x,
    const float* __restrict__ ea_in,
    float* __restrict__ ea_out,
    const int* __restrict__ src_idx,
    const int* __restrict__ dst_idx,
    const _Float16* __restrict__ w1f,
    const float* __restrict__ b1,
    const _Float16* __restrict__ w2f,
    const float* __restrict__ b2,
    float* __restrict__ agg,
    int E)
{
    __shared__ __align__(16) _Float16 sA[64][PWS];

    const int t    = threadIdx.x;
    const int lane = t & 63;
    const int w    = t >> 6;
    const int col  = lane & 15;
    const int g    = lane >> 4;
    const int ko   = g * 8;
    const long base = (long)blockIdx.x * 64;

    // this lane's own A-row (edge id) — dst kept for the shfl'd epilogue
    long er0 = base + w * 16 + col;
    if (er0 >= E) er0 = E - 1;
    const int di = dst_idx[er0];

    // ---- upfront loads: rows it*4+g of the wave tile, cols col*4..+4 ----
    float4 ea4[4], sx4[4], dx4[4];
#pragma unroll
    for (int it = 0; it < 4; ++it) {
        long er = base + w * 16 + it * 4 + g;
        if (er >= E) er = E - 1;
        ea4[it] = *(const float4*)(ea_in + er * 64 + col * 4);
        sx4[it] = *(const float4*)(x + (long)src_idx[er] * 64 + col * 4);
        dx4[it] = *(const float4*)(x + (long)dst_idx[er] * 64 + col * 4);
    }

    f32x4 acc[4];
#pragma unroll
    for (int nf = 0; nf < 4; ++nf) {
        float bv = b1[nf * 16 + col];
        acc[nf] = (f32x4){bv, bv, bv, bv};
    }

    const int arow = w * 16 + col;

#define SEGMENT(s3, SRC)                                                        \
    {                                                                           \
        _Pragma("unroll")                                                       \
        for (int it = 0; it < 4; ++it) {                                        \
            int rg = w * 16 + it * 4 + g;                                       \
            f16x4 hv;                                                           \
            hv[0] = (_Float16)SRC[it].x; hv[1] = (_Float16)SRC[it].y;           \
            hv[2] = (_Float16)SRC[it].z; hv[3] = (_Float16)SRC[it].w;           \
            *(f16x4*)&sA[rg][col * 4] = hv;                                     \
        }                                                                       \
        _Pragma("unroll")                                                       \
        for (int tt = 0; tt < 2; ++tt) {                                        \
            int k0 = tt * 32 + ko;                                              \
            f16x8 af = *(const f16x8*)&sA[arow][k0];                            \
            int tg = (s3) * 2 + tt;                                             \
            _Pragma("unroll")                                                   \
            for (int nf = 0; nf < 4; ++nf) {                                    \
                f16x8 bf = *(const f16x8*)(w1f + (size_t)((tg*4+nf)*64+lane)*8);\
                acc[nf] = __builtin_amdgcn_mfma_f32_16x16x32_f16(af, bf, acc[nf], 0, 0, 0); \
            }                                                                   \
        }                                                                       \
    }

    SEGMENT(0, ea4)    // edge_attr  (k 0..63)
    SEGMENT(1, sx4)    // x[src]     (k 64..127)
    SEGMENT(2, dx4)    // x[dst]     (k 128..191)
#undef SEGMENT

    // ---- silu -> h staged into the wave's own 16 LDS rows (C-frag layout) ----
#pragma unroll
    for (int nf = 0; nf < 4; ++nf)
#pragma unroll
        for (int rg = 0; rg < 4; ++rg) {
            int row = w * 16 + g * 4 + rg;
            sA[row][nf * 16 + col] = (_Float16)silu_f(acc[nf][rg]);
        }

    // ---- layer-2 GEMM (K=64) ----
    f32x4 out[4];
#pragma unroll
    for (int nf = 0; nf < 4; ++nf) {
        float bv = b2[nf * 16 + col];
        out[nf] = (f32x4){bv, bv, bv, bv};
    }
#pragma unroll
    for (int tt = 0; tt < 2; ++tt) {
        int k0 = tt * 32 + ko;
        f16x8 af = *(const f16x8*)&sA[arow][k0];
#pragma unroll
        for (int nf = 0; nf < 4; ++nf) {
            f16x8 bf = *(const f16x8*)(w2f + (size_t)((tt * 4 + nf) * 64 + lane) * 8);
            out[nf] = __builtin_amdgcn_mfma_f32_16x16x32_f16(af, bf, out[nf], 0, 0, 0);
        }
    }

    // ---- epilogue: plain stores + transposed atomic scatter ----
    const int rbase = w * 16 + g * 4;
#pragma unroll
    for (int rg = 0; rg < 4; ++rg) {
        long row = base + rbase + rg;
        if (row < E) {
            int drow = __shfl(di, g * 4 + rg);   // lane col==g*4+rg holds this row's dst
            float* op = ea_out + row * 64;
            float* ap = agg + (long)drow * 64;
#pragma unroll
            for (int nf = 0; nf < 4; ++nf) {
                op[nf * 16 + col] = out[nf][rg];
                atomicAdd(&ap[nf * 16 + col], out[nf][rg]);
            }
        }
    }
}

// ---------------------------------------------------------------------------
// Node kernel: direct A-fragment loads (x, agg rows sequential), LDS only for
// the h transpose. Single-pass f16. No atomics.
// ---------------------------------------------------------------------------
__global__ __launch_bounds__(256, 8) void gnn_node_mfma(
    const float* __restrict__ x_in,
    const float* __restrict__ aggp,
    float* __restrict__ x_out,
    const _Float16* __restrict__ w1f,
    const float* __restrict__ b1,
    const _Float16* __restrict__ w2f,
    const float* __restrict__ b2, int N)
{
    __shared__ __align__(16) _Float16 sA[64][PWS];

    const int t    = threadIdx.x;
    const int lane = t & 63;
    const int w    = t >> 6;
    const int col  = lane & 15;
    const int g    = lane >> 4;
    const int ko   = g * 8;
    const long base = (long)blockIdx.x * 64;

    long nr = base + w * 16 + col;
    if (nr >= N) nr = N - 1;
    const float* px = x_in + nr * 64 + ko;
    const float* pa = aggp + nr * 64 + ko;

    float4 v0 = *(const float4*)(px);
    float4 v1 = *(const float4*)(px + 4);
    float4 v2 = *(const float4*)(px + 32);
    float4 v3 = *(const float4*)(px + 36);
    float4 v4 = *(const float4*)(pa);
    float4 v5 = *(const float4*)(pa + 4);
    float4 v6 = *(const float4*)(pa + 32);
    float4 v7 = *(const float4*)(pa + 36);

    f32x4 acc[4];
#pragma unroll
    for (int nf = 0; nf < 4; ++nf) {
        float bv = b1[nf * 16 + col];
        acc[nf] = (f32x4){bv, bv, bv, bv};
    }

#define QTR(m, A, B)                                                            \
    {                                                                           \
        f16x8 af;                                                               \
        af[0] = (_Float16)A.x; af[1] = (_Float16)A.y;                           \
        af[2] = (_Float16)A.z; af[3] = (_Float16)A.w;                           \
        af[4] = (_Float16)B.x; af[5] = (_Float16)B.y;                           \
        af[6] = (_Float16)B.z; af[7] = (_Float16)B.w;                           \
        _Pragma("unroll")                                                       \
        for (int nf = 0; nf < 4; ++nf) {                                        \
            f16x8 bf = *(const f16x8*)(w1f + (size_t)(((m)*4+nf)*64+lane)*8);   \
            acc[nf] = __builtin_amdgcn_mfma_f32_16x16x32_f16(af, bf, acc[nf], 0, 0, 0); \
        }                                                                       \
    }
    QTR(0, v0, v1)  QTR(1, v2, v3)   // x    (k 0..63)
    QTR(2, v4, v5)  QTR(3, v6, v7)   // agg  (k 64..127)
#undef QTR

#pragma unroll
    for (int nf = 0; nf < 4; ++nf)
#pragma unroll
        for (int rg = 0; rg < 4; ++rg) {
            int row = w * 16 + g * 4 + rg;
            sA[row][nf * 16 + col] = (_Float16)silu_f(acc[nf][rg]);
        }

    f32x4 out[4];
#pragma unroll
    for (int nf = 0; nf < 4; ++nf) {
        float bv = b2[nf * 16 + col];
        out[nf] = (f32x4){bv, bv, bv, bv};
    }
    const int arow = w * 16 + col;
#pragma unroll
    for (int tt = 0; tt < 2; ++tt) {
        int k0 = tt * 32 + ko;
        f16x8 af = *(const f16x8*)&sA[arow][k0];
#pragma unroll
        for (int nf = 0; nf < 4; ++nf) {
            f16x8 bf = *(const f16x8*)(w2f + (size_t)((tt * 4 + nf) * 64 + lane) * 8);
            out[nf] = __builtin_amdgcn_mfma_f32_16x16x32_f16(af, bf, out[nf], 0, 0, 0);
        }
    }

    const int rbase = w * 16 + g * 4;
#pragma unroll
    for (int rg = 0; rg < 4; ++rg) {
        long row = base + rbase + rg;
        if (row < N) {
            float* op = x_out + row * 64;
#pragma unroll
            for (int nf = 0; nf < 4; ++nf)
                op[nf * 16 + col] = out[nf][rg];
        }
    }
}

extern "C" void kernel_launch(void* const* d_in, const int* in_sizes, int n_in,
                              void* d_out, int out_size, void* d_ws, size_t ws_size,
                              hipStream_t stream) {
    const int H = 64;
    const int N = in_sizes[0] / H;   // 50000
    const int E = in_sizes[1] / H;   // 800000

    const float* x0  = (const float*)d_in[0];
    const float* ea0 = (const float*)d_in[1];
    const int*   ei  = (const int*)d_in[2];
    const float* ew1 = (const float*)d_in[3];
    const float* eb1 = (const float*)d_in[4];
    const float* ew2 = (const float*)d_in[5];
    const float* eb2 = (const float*)d_in[6];
    const float* nw1 = (const float*)d_in[7];
    const float* nb1 = (const float*)d_in[8];
    const float* nw2 = (const float*)d_in[9];
    const float* nb2 = (const float*)d_in[10];

    float* outX = (float*)d_out;                 // [N, H]
    float* outE = outX + (size_t)N * H;          // [E, H]

    float* agg      = (float*)d_ws;              // [N, H] fp32
    _Float16* wbase = (_Float16*)(agg + (size_t)N * H);

    const int* srcI = ei;
    const int* dstI = ei + E;

    WPack pack;
    size_t off = 0;
    _Float16* EW1[2]; _Float16* EW2[2]; _Float16* NW1[2]; _Float16* NW2[2];
    for (int l = 0; l < 2; ++l) {
        EW1[l] = wbase + off; off += 192 * 64;
        EW2[l] = wbase + off; off += 64 * 64;
        NW1[l] = wbase + off; off += 128 * 64;
        NW2[l] = wbase + off; off += 64 * 64;
        pack.d[l * 4 + 0] = {ew1 + (size_t)l * 192 * 64, EW1[l], 192};
        pack.d[l * 4 + 1] = {ew2 + (size_t)l * 64 * 64,  EW2[l], 64};
        pack.d[l * 4 + 2] = {nw1 + (size_t)l * 128 * 64, NW1[l], 128};
        pack.d[l * 4 + 3] = {nw2 + (size_t)l * 64 * 64,  NW2[l], 64};
    }
    conv_weights<<<dim3(48, 8), 256, 0, stream>>>(pack);

    const int egrid = (E + 63) / 64;
    const int ngrid = (N + 63) / 64;
    const size_t aggBytes = (size_t)N * H * sizeof(float);

    for (int l = 0; l < 2; ++l) {
        const float* xin  = (l == 0) ? x0  : outX;
        const float* eain = (l == 0) ? ea0 : outE;
        (void)hipMemsetAsync(agg, 0, aggBytes, stream);
        gnn_edge_mfma<<<egrid, 256, 0, stream>>>(
            xin, eain, outE, srcI, dstI,
            EW1[l], eb1 + l * H,
            EW2[l], eb2 + l * H,
            agg, E);
        gnn_node_mfma<<<ngrid, 256, 0, stream>>>(
            xin, agg, outX,
            NW1[l], nb1 + l * H,
            NW2[l], nb2 + l * H,
            N);
    }
}

// Round 10
// 540.336 us; speedup vs baseline: 1.4961x; 1.0002x over previous
//
#include <hip/hip_runtime.h>

typedef __attribute__((ext_vector_type(8))) _Float16 f16x8;
typedef __attribute__((ext_vector_type(4))) _Float16 f16x4;
typedef __attribute__((ext_vector_type(4))) float f32x4;

#define PWS 72   // LDS tile pitch in halfs: 144B rows, 16B-aligned chunks

__device__ __forceinline__ float silu_f(float v) {
    return v * (1.0f / (1.0f + __expf(-v)));
}

// ---------------------------------------------------------------------------
// Weight pre-conversion: fp32 [K][64] -> f16 in B-fragment order:
//   out[((t*4+nf)*64 + lane)*8 + j] = W[t*32 + (lane>>4)*8 + j][nf*16 + (lane&15)]
// ---------------------------------------------------------------------------
struct WDesc { const float* W; _Float16* out; int K; };
struct WPack { WDesc d[8]; };

__global__ __launch_bounds__(256) void conv_weights(WPack p) {
    WDesc wd = p.d[blockIdx.y];
    int total = wd.K * 64;
    int i = blockIdx.x * 256 + threadIdx.x;
    if (i >= total) return;
    int j  = i & 7;
    int l  = (i >> 3) & 63;
    int tn = i >> 9;                 // t*4 + nf
    int t  = tn >> 2, nf = tn & 3;
    int k  = t * 32 + (l >> 4) * 8 + j;
    int c  = nf * 16 + (l & 15);
    wd.out[i] = (_Float16)wd.W[k * 64 + c];   // RNE
}

// ---------------------------------------------------------------------------
// Edge kernel: 4 independent waves/block, wave owns 16 edges. Upfront loads
// -> convert to f16 -> LDS -> MFMA per segment (wave-private rows, no
// barriers). Single-pass f16 MFMA. Epilogue: ea_out store (fp32 or f16 per
// template) + transposed fp32 atomic scatter into agg.
// IN16:  read inter-layer edge_attr as f16 (half fetch, no convert VALU).
// OUT16: write inter-layer edge_attr as f16 (half write).
// ---------------------------------------------------------------------------
template <bool IN16, bool OUT16>
__global__ __launch_bounds__(256, 8) void gnn_edge_mfma(
    const float* __restrict__ x,
    const float* __restrict__ ea_in,
    const _Float16* __restrict__ ea_in16,
    float* __restrict__ ea_out,
    _Float16* __restrict__ ea_out16,
    const int* __restrict__ src_idx,
    const int* __restrict__ dst_idx,
    const _Float16* __restrict__ w1f,
    const float* __restrict__ b1,
    const _Float16* __restrict__ w2f,
    const float* __restrict__ b2,
    float* __restrict__ agg,
    int E)
{
    __shared__ __align__(16) _Float16 sA[64][PWS];

    const int t    = threadIdx.x;
    const int lane = t & 63;
    const int w    = t >> 6;
    const int col  = lane & 15;
    const int g    = lane >> 4;
    const int ko   = g * 8;
    const long base = (long)blockIdx.x * 64;

    // this lane's own A-row (edge id) — dst kept for the shfl'd epilogue
    long er0 = base + w * 16 + col;
    if (er0 >= E) er0 = E - 1;
    const int di = dst_idx[er0];

    // ---- upfront loads: rows it*4+g of the wave tile, cols col*4..+4 ----
    f16x4  ea16v[4];
    float4 ea4[4];
    float4 sx4[4], dx4[4];
#pragma unroll
    for (int it = 0; it < 4; ++it) {
        long er = base + w * 16 + it * 4 + g;
        if (er >= E) er = E - 1;
        if constexpr (IN16) ea16v[it] = *(const f16x4*)(ea_in16 + er * 64 + col * 4);
        else                ea4[it]   = *(const float4*)(ea_in   + er * 64 + col * 4);
        sx4[it] = *(const float4*)(x + (long)src_idx[er] * 64 + col * 4);
        dx4[it] = *(const float4*)(x + (long)dst_idx[er] * 64 + col * 4);
    }

    f32x4 acc[4];
#pragma unroll
    for (int nf = 0; nf < 4; ++nf) {
        float bv = b1[nf * 16 + col];
        acc[nf] = (f32x4){bv, bv, bv, bv};
    }

    const int arow = w * 16 + col;

#define MFMA_L1(s3)                                                             \
    _Pragma("unroll")                                                           \
    for (int tt = 0; tt < 2; ++tt) {                                            \
        int k0 = tt * 32 + ko;                                                  \
        f16x8 af = *(const f16x8*)&sA[arow][k0];                                \
        int tg = (s3) * 2 + tt;                                                 \
        _Pragma("unroll")                                                       \
        for (int nf = 0; nf < 4; ++nf) {                                        \
            f16x8 bf = *(const f16x8*)(w1f + (size_t)((tg*4+nf)*64+lane)*8);    \
            acc[nf] = __builtin_amdgcn_mfma_f32_16x16x32_f16(af, bf, acc[nf], 0, 0, 0); \
        }                                                                       \
    }

    // ---- segment 0: edge_attr (k 0..63) ----
#pragma unroll
    for (int it = 0; it < 4; ++it) {
        int rg = w * 16 + it * 4 + g;
        f16x4 hv;
        if constexpr (IN16) {
            hv = ea16v[it];
        } else {
            hv[0] = (_Float16)ea4[it].x; hv[1] = (_Float16)ea4[it].y;
            hv[2] = (_Float16)ea4[it].z; hv[3] = (_Float16)ea4[it].w;
        }
        *(f16x4*)&sA[rg][col * 4] = hv;
    }
    MFMA_L1(0)

    // ---- segment 1: x[src] (k 64..127) ----
#pragma unroll
    for (int it = 0; it < 4; ++it) {
        int rg = w * 16 + it * 4 + g;
        f16x4 hv;
        hv[0] = (_Float16)sx4[it].x; hv[1] = (_Float16)sx4[it].y;
        hv[2] = (_Float16)sx4[it].z; hv[3] = (_Float16)sx4[it].w;
        *(f16x4*)&sA[rg][col * 4] = hv;
    }
    MFMA_L1(1)

    // ---- segment 2: x[dst] (k 128..191) ----
#pragma unroll
    for (int it = 0; it < 4; ++it) {
        int rg = w * 16 + it * 4 + g;
        f16x4 hv;
        hv[0] = (_Float16)dx4[it].x; hv[1] = (_Float16)dx4[it].y;
        hv[2] = (_Float16)dx4[it].z; hv[3] = (_Float16)dx4[it].w;
        *(f16x4*)&sA[rg][col * 4] = hv;
    }
    MFMA_L1(2)
#undef MFMA_L1

    // ---- silu -> h staged into the wave's own 16 LDS rows (C-frag layout) ----
#pragma unroll
    for (int nf = 0; nf < 4; ++nf)
#pragma unroll
        for (int rg = 0; rg < 4; ++rg) {
            int row = w * 16 + g * 4 + rg;
            sA[row][nf * 16 + col] = (_Float16)silu_f(acc[nf][rg]);
        }

    // ---- layer-2 GEMM (K=64) ----
    f32x4 out[4];
#pragma unroll
    for (int nf = 0; nf < 4; ++nf) {
        float bv = b2[nf * 16 + col];
        out[nf] = (f32x4){bv, bv, bv, bv};
    }
#pragma unroll
    for (int tt = 0; tt < 2; ++tt) {
        int k0 = tt * 32 + ko;
        f16x8 af = *(const f16x8*)&sA[arow][k0];
#pragma unroll
        for (int nf = 0; nf < 4; ++nf) {
            f16x8 bf = *(const f16x8*)(w2f + (size_t)((tt * 4 + nf) * 64 + lane) * 8);
            out[nf] = __builtin_amdgcn_mfma_f32_16x16x32_f16(af, bf, out[nf], 0, 0, 0);
        }
    }

    // ---- epilogue: ea_out store + transposed fp32 atomic scatter ----
    const int rbase = w * 16 + g * 4;
#pragma unroll
    for (int rg = 0; rg < 4; ++rg) {
        long row = base + rbase + rg;
        if (row < E) {
            int drow = __shfl(di, g * 4 + rg);   // lane col==g*4+rg holds this row's dst
            float* ap = agg + (long)drow * 64;
#pragma unroll
            for (int nf = 0; nf < 4; ++nf) {
                if constexpr (OUT16)
                    ea_out16[row * 64 + nf * 16 + col] = (_Float16)out[nf][rg];
                else
                    ea_out[row * 64 + nf * 16 + col] = out[nf][rg];
                atomicAdd(&ap[nf * 16 + col], out[nf][rg]);
            }
        }
    }
}

// ---------------------------------------------------------------------------
// Node kernel: direct A-fragment loads (x, agg rows sequential), LDS only for
// the h transpose. Single-pass f16. No atomics.
// ---------------------------------------------------------------------------
__global__ __launch_bounds__(256, 8) void gnn_node_mfma(
    const float* __restrict__ x_in,
    const float* __restrict__ aggp,
    float* __restrict__ x_out,
    const _Float16* __restrict__ w1f,
    const float* __restrict__ b1,
    const _Float16* __restrict__ w2f,
    const float* __restrict__ b2, int N)
{
    __shared__ __align__(16) _Float16 sA[64][PWS];

    const int t    = threadIdx.x;
    const int lane = t & 63;
    const int w    = t >> 6;
    const int col  = lane & 15;
    const int g    = lane >> 4;
    const int ko   = g * 8;
    const long base = (long)blockIdx.x * 64;

    long nr = base + w * 16 + col;
    if (nr >= N) nr = N - 1;
    const float* px = x_in + nr * 64 + ko;
    const float* pa = aggp + nr * 64 + ko;

    float4 v0 = *(const float4*)(px);
    float4 v1 = *(const float4*)(px + 4);
    float4 v2 = *(const float4*)(px + 32);
    float4 v3 = *(const float4*)(px + 36);
    float4 v4 = *(const float4*)(pa);
    float4 v5 = *(const float4*)(pa + 4);
    float4 v6 = *(const float4*)(pa + 32);
    float4 v7 = *(const float4*)(pa + 36);

    f32x4 acc[4];
#pragma unroll
    for (int nf = 0; nf < 4; ++nf) {
        float bv = b1[nf * 16 + col];
        acc[nf] = (f32x4){bv, bv, bv, bv};
    }

#define QTR(m, A, B)                                                            \
    {                                                                           \
        f16x8 af;                                                               \
        af[0] = (_Float16)A.x; af[1] = (_Float16)A.y;                           \
        af[2] = (_Float16)A.z; af[3] = (_Float16)A.w;                           \
        af[4] = (_Float16)B.x; af[5] = (_Float16)B.y;                           \
        af[6] = (_Float16)B.z; af[7] = (_Float16)B.w;                           \
        _Pragma("unroll")                                                       \
        for (int nf = 0; nf < 4; ++nf) {                                        \
            f16x8 bf = *(const f16x8*)(w1f + (size_t)(((m)*4+nf)*64+lane)*8);   \
            acc[nf] = __builtin_amdgcn_mfma_f32_16x16x32_f16(af, bf, acc[nf], 0, 0, 0); \
        }                                                                       \
    }
    QTR(0, v0, v1)  QTR(1, v2, v3)   // x    (k 0..63)
    QTR(2, v4, v5)  QTR(3, v6, v7)   // agg  (k 64..127)
#undef QTR

#pragma unroll
    for (int nf = 0; nf < 4; ++nf)
#pragma unroll
        for (int rg = 0; rg < 4; ++rg) {
            int row = w * 16 + g * 4 + rg;
            sA[row][nf * 16 + col] = (_Float16)silu_f(acc[nf][rg]);
        }

    f32x4 out[4];
#pragma unroll
    for (int nf = 0; nf < 4; ++nf) {
        float bv = b2[nf * 16 + col];
        out[nf] = (f32x4){bv, bv, bv, bv};
    }
    const int arow = w * 16 + col;
#pragma unroll
    for (int tt = 0; tt < 2; ++tt) {
        int k0 = tt * 32 + ko;
        f16x8 af = *(const f16x8*)&sA[arow][k0];
#pragma unroll
        for (int nf = 0; nf < 4; ++nf) {
            f16x8 bf = *(const f16x8*)(w2f + (size_t)((tt * 4 + nf) * 64 + lane) * 8);
            out[nf] = __builtin_amdgcn_mfma_f32_16x16x32_f16(af, bf, out[nf], 0, 0, 0);
        }
    }

    const int rbase = w * 16 + g * 4;
#pragma unroll
    for (int rg = 0; rg < 4; ++rg) {
        long row = base + rbase + rg;
        if (row < N) {
            float* op = x_out + row * 64;
#pragma unroll
            for (int nf = 0; nf < 4; ++nf)
                op[nf * 16 + col] = out[nf][rg];
        }
    }
}

extern "C" void kernel_launch(void* const* d_in, const int* in_sizes, int n_in,
                              void* d_out, int out_size, void* d_ws, size_t ws_size,
                              hipStream_t stream) {
    const int H = 64;
    const int N = in_sizes[0] / H;   // 50000
    const int E = in_sizes[1] / H;   // 800000

    const float* x0  = (const float*)d_in[0];
    const float* ea0 = (const float*)d_in[1];
    const int*   ei  = (const int*)d_in[2];
    const float* ew1 = (const float*)d_in[3];
    const float* eb1 = (const float*)d_in[4];
    const float* ew2 = (const float*)d_in[5];
    const float* eb2 = (const float*)d_in[6];
    const float* nw1 = (const float*)d_in[7];
    const float* nb1 = (const float*)d_in[8];
    const float* nw2 = (const float*)d_in[9];
    const float* nb2 = (const float*)d_in[10];

    float* outX = (float*)d_out;                 // [N, H]
    float* outE = outX + (size_t)N * H;          // [E, H]

    // workspace carve: agg | weight frags | (optional) f16 inter-layer ea
    const size_t aggBytes = (size_t)N * H * sizeof(float);
    const size_t wElems   = 2 * ((size_t)(192 + 64 + 128 + 64) * 64);
    const size_t eaHBytes = (size_t)E * H * sizeof(_Float16);

    float* agg      = (float*)d_ws;
    _Float16* wbase = (_Float16*)((char*)d_ws + aggBytes);
    char* eaH_raw   = (char*)(wbase + wElems);
    eaH_raw = (char*)(((uintptr_t)eaH_raw + 15) & ~(uintptr_t)15);
    _Float16* eaH   = (_Float16*)eaH_raw;

    const bool useF16 = ((char*)eaH + eaHBytes) <= ((char*)d_ws + ws_size);

    const int* srcI = ei;
    const int* dstI = ei + E;

    WPack pack;
    size_t off = 0;
    _Float16* EW1[2]; _Float16* EW2[2]; _Float16* NW1[2]; _Float16* NW2[2];
    for (int l = 0; l < 2; ++l) {
        EW1[l] = wbase + off; off += 192 * 64;
        EW2[l] = wbase + off; off += 64 * 64;
        NW1[l] = wbase + off; off += 128 * 64;
        NW2[l] = wbase + off; off += 64 * 64;
        pack.d[l * 4 + 0] = {ew1 + (size_t)l * 192 * 64, EW1[l], 192};
        pack.d[l * 4 + 1] = {ew2 + (size_t)l * 64 * 64,  EW2[l], 64};
        pack.d[l * 4 + 2] = {nw1 + (size_t)l * 128 * 64, NW1[l], 128};
        pack.d[l * 4 + 3] = {nw2 + (size_t)l * 64 * 64,  NW2[l], 64};
    }
    conv_weights<<<dim3(48, 8), 256, 0, stream>>>(pack);

    const int egrid = (E + 63) / 64;
    const int ngrid = (N + 63) / 64;

    for (int l = 0; l < 2; ++l) {
        const float* xin = (l == 0) ? x0 : outX;
        (void)hipMemsetAsync(agg, 0, aggBytes, stream);
        if (useF16) {
            if (l == 0) {
                // layer 1: fp32 input ea -> f16 intermediate ea
                gnn_edge_mfma<false, true><<<egrid, 256, 0, stream>>>(
                    xin, ea0, nullptr, nullptr, eaH, srcI, dstI,
                    EW1[l], eb1 + l * H, EW2[l], eb2 + l * H, agg, E);
            } else {
                // layer 2: f16 intermediate ea -> fp32 final ea
                gnn_edge_mfma<true, false><<<egrid, 256, 0, stream>>>(
                    xin, nullptr, eaH, outE, nullptr, srcI, dstI,
                    EW1[l], eb1 + l * H, EW2[l], eb2 + l * H, agg, E);
            }
        } else {
            const float* eain = (l == 0) ? ea0 : outE;
            gnn_edge_mfma<false, false><<<egrid, 256, 0, stream>>>(
                xin, eain, nullptr, outE, nullptr, srcI, dstI,
                EW1[l], eb1 + l * H, EW2[l], eb2 + l * H, agg, E);
        }
        gnn_node_mfma<<<ngrid, 256, 0, stream>>>(
            xin, agg, outX,
            NW1[l], nb1 + l * H,
            NW2[l], nb2 + l * H,
            N);
    }
}